// Round 1
// baseline (88.192 us; speedup 1.0000x reference)
//
#include <hip/hip_runtime.h>

// KDE gaussian: out[k][b] = (1/(LEN*bw*sqrt(2pi))) * sum_i exp(-0.5*((x[b][i]-c[k])/bw)^2)
// bw = 0.1. Fold into 2^(-(S*(x-c))^2) with S = sqrt(0.5*log2(e))/bw so the inner
// loop is sub/mul/exp2(neg-modifier)/add — 4 VALU instrs per pair, exp-pipe bound.

constexpr int KPTS   = 256;  // grid points == blockDim.x
constexpr int CHUNK  = 512;  // samples staged per block

__global__ __launch_bounds__(KPTS) void kde_kernel(
    const float* __restrict__ data, const float* __restrict__ c_X,
    float* __restrict__ out, int LEN, int B) {
  __shared__ float xs[CHUNK];

  const int k     = threadIdx.x;   // 0..255 -> grid point
  const int chunk = blockIdx.x;    // sample chunk within batch row
  const int b     = blockIdx.y;    // batch row

  // S = sqrt(0.5 * log2(e)) / bw ; bw = 0.1
  const float S = 8.49321736f;

  // Stage CHUNK samples (pre-scaled by S) into LDS: 128 float4 loads, coalesced.
  const float* src = data + (size_t)b * LEN + (size_t)chunk * CHUNK;
  if (threadIdx.x < CHUNK / 4) {
    float4 v = ((const float4*)src)[threadIdx.x];
    float4 w;
    w.x = v.x * S; w.y = v.y * S; w.z = v.z * S; w.w = v.w * S;
    ((float4*)xs)[threadIdx.x] = w;
  }
  __syncthreads();

  const float cs = c_X[k] * S;

  float a0 = 0.f, a1 = 0.f, a2 = 0.f, a3 = 0.f;
#pragma unroll 4
  for (int i = 0; i < CHUNK / 4; ++i) {
    float4 x = ((const float4*)xs)[i];   // LDS broadcast (same addr all lanes)
    float t0 = x.x - cs;
    float t1 = x.y - cs;
    float t2 = x.z - cs;
    float t3 = x.w - cs;
    a0 += __builtin_amdgcn_exp2f(-(t0 * t0));
    a1 += __builtin_amdgcn_exp2f(-(t1 * t1));
    a2 += __builtin_amdgcn_exp2f(-(t2 * t2));
    a3 += __builtin_amdgcn_exp2f(-(t3 * t3));
  }

  // norm = (1/bw) * (1/sqrt(2pi)) / LEN
  const float norm = 3.98942280f / (float)LEN;
  atomicAdd(&out[(size_t)k * B + b], (a0 + a1 + a2 + a3) * norm);
}

extern "C" void kernel_launch(void* const* d_in, const int* in_sizes, int n_in,
                              void* d_out, int out_size, void* d_ws, size_t ws_size,
                              hipStream_t stream) {
  const float* data = (const float*)d_in[0];
  // d_in[1] is `dim` (= -1): with last-axis reduction, data layout is already [B, LEN]
  const float* c_X  = (const float*)d_in[2];
  float* out        = (float*)d_out;

  const int B   = 16;
  const int LEN = in_sizes[0] / B;        // 32768

  // d_out is poisoned to 0xAA before every timed launch — zero it (capture-safe).
  hipMemsetAsync(d_out, 0, (size_t)out_size * sizeof(float), stream);

  dim3 grid(LEN / CHUNK, B);              // (64, 16) = 1024 blocks
  kde_kernel<<<grid, KPTS, 0, stream>>>(data, c_X, out, LEN, B);
}